// Round 7
// baseline (163.920 us; speedup 1.0000x reference)
//
#include <hip/hip_runtime.h>
#include <stdint.h>

#define NB    1024   // batch
#define NUM   512    // nodes
#define HD    64     // hidden dim
#define NE    4096   // edges
#define NEP   4608   // padded edge capacity (each column padded to even count)
#define MAIN  10     // softmax segment

typedef _Float16 hlf;
typedef __attribute__((ext_vector_type(2))) _Float16 hlf2;
typedef __attribute__((ext_vector_type(8))) _Float16 hlf8;
typedef __attribute__((ext_vector_type(4))) float f32x4;

__device__ __forceinline__ unsigned short f2h(float f) {
    hlf v = (hlf)f;
    return __builtin_bit_cast(unsigned short, v);
}

// ---------------------------------------------------------------------------
// Prep: block 0 builds degree-sorted, even-padded CSR via wave-shfl scans;
// blocks 1..72 cast E1 = emb@W1 and W2T = W2^T to f16.
// Edge pack: epk = (row << 16) | f16(norm).
// ---------------------------------------------------------------------------
__global__ __launch_bounds__(512) void prep_all(
    const int* __restrict__ erow, const int* __restrict__ ecol,
    const float* __restrict__ emb, const float* __restrict__ W1,
    const float* __restrict__ W2,
    int* __restrict__ rsptr, int* __restrict__ colmap, int* __restrict__ epk,
    short* __restrict__ E1, short* __restrict__ W2T)
{
    const int t = threadIdx.x;
    if (blockIdx.x != 0) {
        int g = (blockIdx.x - 1) * 512 + t;     // 72 x 512 = 36864
        if (g < NUM * HD) {
            int node = g >> 6, dim = g & 63;
            float acc = 0.0f;
            #pragma unroll
            for (int k = 0; k < HD; ++k) acc += emb[node * HD + k] * W1[k * HD + dim];
            E1[g] = (short)f2h(acc);
        } else if (g < NUM * HD + HD * HD) {
            int j = g - NUM * HD;
            int dout = j >> 6, din = j & 63;
            W2T[j] = (short)f2h(W2[din * HD + dout]);
        }
        return;
    }

    __shared__ int   sdeg[NUM];     // degree -> bin cursor -> edge cursor
    __shared__ int   aux[NUM];      // histogram scan -> rank starts
    __shared__ float sdv[NUM];
    __shared__ int   rnk[NUM];
    __shared__ int   rdg[NUM];      // padded degree by rank
    __shared__ int   wsum[8];

    const int lane = t & 63, wv = t >> 6;

    sdeg[t] = 0; aux[t] = 0;
    __syncthreads();
    for (int e = t; e < NE; e += 512) atomicAdd(&sdeg[ecol[e]], 1);
    __syncthreads();
    const int deg  = sdeg[t];
    const int pdeg = (deg + 1) & ~1;            // pad to even
    const int dbin = deg < NUM ? deg : NUM - 1;
    sdv[t] = deg > 0 ? rsqrtf((float)deg) : 0.0f;
    atomicAdd(&aux[dbin], 1);
    __syncthreads();
    // scan histogram (shfl)
    {
        int v = aux[t];
        #pragma unroll
        for (int ofs = 1; ofs < 64; ofs <<= 1) {
            int sh = __shfl_up(v, ofs, 64);
            if (lane >= ofs) v += sh;
        }
        if (lane == 63) wsum[wv] = v;
        __syncthreads();
        if (t == 0) {
            int s = 0;
            #pragma unroll
            for (int w = 0; w < 8; ++w) { int tmp = wsum[w]; wsum[w] = s; s += tmp; }
        }
        __syncthreads();
        int inc = v + wsum[wv];
        aux[t]  = inc;                          // inclusive histogram scan
        __syncthreads();
        sdeg[t] = (t == 0) ? 0 : aux[t - 1];    // bin cursors (exclusive)
        __syncthreads();
    }
    {
        int r = atomicAdd(&sdeg[dbin], 1);      // degree-sorted rank
        rnk[t] = r;
        rdg[r] = pdeg;
        colmap[r] = t;
    }
    __syncthreads();
    // scan padded degrees by rank -> rank CSR (all-even offsets)
    {
        int dv = rdg[t], v = dv;
        #pragma unroll
        for (int ofs = 1; ofs < 64; ofs <<= 1) {
            int sh = __shfl_up(v, ofs, 64);
            if (lane >= ofs) v += sh;
        }
        if (lane == 63) wsum[wv] = v;
        __syncthreads();
        if (t == 0) {
            int s = 0;
            #pragma unroll
            for (int w = 0; w < 8; ++w) { int tmp = wsum[w]; wsum[w] = s; s += tmp; }
        }
        __syncthreads();
        int inc  = v + wsum[wv];
        int excl = inc - dv;
        rsptr[t] = excl;
        if (t == NUM - 1) rsptr[NUM] = inc;
        aux[t] = excl;                          // rank start
        __syncthreads();
    }
    sdeg[t] = aux[rnk[t]];                      // per-ORIGINAL-col edge cursor
    __syncthreads();
    for (int i = t; i < NEP; i += 512) epk[i] = 0;   // zero pads
    __syncthreads();
    for (int e = t; e < NE; e += 512) {
        int c = ecol[e], rr = erow[e];
        int p = atomicAdd(&sdeg[c], 1);
        unsigned ns = (unsigned)f2h(sdv[rr] * sdv[c]);
        epk[p] = (rr << 16) | (int)ns;          // hi16 = row index
    }
}

// ---------------------------------------------------------------------------
// Body: one block (1024 thr) per BATCH PAIR (b0 = 2*blk, b1 = 2*blk+1).
// The edge/chain structure is batch-invariant, so each latency chain is
// traversed once per pair instead of once per element (blocks halve).
// Commuted flow (single H buffer):
//   SpMM1: h1pair = relu(S@(x*E1) + b1)  E1 gathered from L2 (one 128B row
//          serves both elements); H rows = [node][b0 dims | b1 dims] (256B)
//   8 stripe sets: SpMM2 gathers pair-rows (1 b128/lane over 16-lane groups)
//          -> swizzled 64x128h stripe -> MFMA z2=agg2@W2+b2 -> tv += relu.W3
//   SpMM3: logits = S@tv + b3; softmax/sigmoid per element.
// ---------------------------------------------------------------------------
__global__ __launch_bounds__(1024, 4) void gcn_body(
    const float* __restrict__ x, const hlf* __restrict__ E1,
    const hlf* __restrict__ W2T,
    const float* __restrict__ b1, const float* __restrict__ b2,
    const float* __restrict__ W3, const float* __restrict__ b3,
    const int* __restrict__ rsptrg, const int* __restrict__ cmapg,
    const int* __restrict__ epkg,
    float* __restrict__ out)
{
    __shared__ hlf   H[NUM * 128];     // 131072 B h1-pair rows [node][b0:64|b1:64]
    __shared__ hlf   SP[64 * 128];     // 16384 B stripe (swizzled); slog/sred overlay
    __shared__ float XT[2 * NUM];      // 4096 B: x-pair, then tv-pair accumulator
    __shared__ int   sptr[513];
    __shared__ int   cmap[NUM];

    float* SLOG = (float*)SP;              // 2x512 logits (after last set)
    float* SRED = ((float*)SP) + 2 * NUM;  // 4 floats

    const int t    = threadIdx.x;
    const int b0   = blockIdx.x * 2;
    const int lane = t & 63;
    const int wave = t >> 6;           // 0..15
    const int j16  = lane & 15;        // lane within 16-group (== l15)
    const int g16  = lane >> 4;        // group within wave (== q)
    const int bsel = j16 >> 3;         // batch half this lane serves
    const int d8   = (j16 & 7) * 8;    // dim strip within the batch half

    // ---- stage x-pair (contiguous), csr header
    XT[t] = x[b0 * NUM + t];           // [0..511]=b0, [512..1023]=b1
    if (t < 513) sptr[t] = rsptrg[t];
    if (t < NUM) cmap[t] = cmapg[t];

    // per-lane layer-1 bias strip
    float b1v[8];
    {
        f32x4 u0 = *(const f32x4*)&b1[d8], u1 = *(const f32x4*)&b1[d8 + 4];
        #pragma unroll
        for (int j = 0; j < 4; ++j) { b1v[j] = u0[j]; b1v[j + 4] = u1[j]; }
    }
    __syncthreads();

// 8 mixed-precision FMAs: f16 elements of gv times f32 scale sc into a[8]
#define MAC8(a, gv, sc) {                                                     \
        const hlf2 p0 = __builtin_bit_cast(hlf2, (gv).x);                     \
        const hlf2 p1 = __builtin_bit_cast(hlf2, (gv).y);                     \
        const hlf2 p2 = __builtin_bit_cast(hlf2, (gv).z);                     \
        const hlf2 p3 = __builtin_bit_cast(hlf2, (gv).w);                     \
        a[0] = fmaf((float)p0[0], (sc), a[0]);                                \
        a[1] = fmaf((float)p0[1], (sc), a[1]);                                \
        a[2] = fmaf((float)p1[0], (sc), a[2]);                                \
        a[3] = fmaf((float)p1[1], (sc), a[3]);                                \
        a[4] = fmaf((float)p2[0], (sc), a[4]);                                \
        a[5] = fmaf((float)p2[1], (sc), a[5]);                                \
        a[6] = fmaf((float)p3[0], (sc), a[6]);                                \
        a[7] = fmaf((float)p3[1], (sc), a[7]); }

#define E1LD(gv, pe) gv = *(const uint4*)(E1b + (((unsigned)(pe) >> 9) & 0xFF80u));
#define E1SC(sc, pe) sc = (float)__builtin_bit_cast(hlf2, (unsigned)(pe))[0]  \
                          * XB[(unsigned)(pe) >> 16];
#define HLD(gv, pe)  gv = *(const uint4*)(Hb + (((unsigned)(pe) >> 8) & 0x1FF00u));
#define HSC(sc, pe)  sc = (float)__builtin_bit_cast(hlf2, (unsigned)(pe))[0];

    // ---- SpMM1: h1pair = relu(S @ (x*E1) + b1) -> H; E1 gathered from L2.
    // 16-lane group per rank; lane serves (bsel, d8); E1 row shared by halves.
    {
        const char*  E1b = (const char*)E1 + d8 * 2;
        const float* XB  = XT + bsel * NUM;
        #pragma unroll 1
        for (int s = 0; s < 8; ++s) {
            int r  = s * 64 + wave * 4 + g16;
            int e0 = sptr[r], e1 = sptr[r + 1];
            int c  = cmap[r];
            float a[8];
            #pragma unroll
            for (int j = 0; j < 8; ++j) a[j] = 0.0f;
            int e = e0;
            for (; e + 4 <= e1; e += 4) {
                int2 qa = *(const int2*)&epkg[e];
                int2 qb = *(const int2*)&epkg[e + 2];
                uint4 g0, g1, g2, g3; float s0, s1, s2, s3;
                E1LD(g0, qa.x) E1LD(g1, qa.y) E1LD(g2, qb.x) E1LD(g3, qb.y)
                E1SC(s0, qa.x) E1SC(s1, qa.y) E1SC(s2, qb.x) E1SC(s3, qb.y)
                MAC8(a, g0, s0) MAC8(a, g1, s1) MAC8(a, g2, s2) MAC8(a, g3, s3)
            }
            if (e < e1) {   // even-padded -> exactly 2 left
                int2 qa = *(const int2*)&epkg[e];
                uint4 g0, g1; float s0, s1;
                E1LD(g0, qa.x) E1LD(g1, qa.y)
                E1SC(s0, qa.x) E1SC(s1, qa.y)
                MAC8(a, g0, s0) MAC8(a, g1, s1)
            }
            uint4 ov;
            ov.x = __builtin_bit_cast(unsigned, __builtin_amdgcn_cvt_pkrtz(
                       fmaxf(a[0] + b1v[0], 0.0f), fmaxf(a[1] + b1v[1], 0.0f)));
            ov.y = __builtin_bit_cast(unsigned, __builtin_amdgcn_cvt_pkrtz(
                       fmaxf(a[2] + b1v[2], 0.0f), fmaxf(a[3] + b1v[3], 0.0f)));
            ov.z = __builtin_bit_cast(unsigned, __builtin_amdgcn_cvt_pkrtz(
                       fmaxf(a[4] + b1v[4], 0.0f), fmaxf(a[5] + b1v[5], 0.0f)));
            ov.w = __builtin_bit_cast(unsigned, __builtin_amdgcn_cvt_pkrtz(
                       fmaxf(a[6] + b1v[6], 0.0f), fmaxf(a[7] + b1v[7], 0.0f)));
            *(uint4*)((char*)H + c * 256 + bsel * 128 + d8 * 2) = ov;
        }
    }
    __syncthreads();
    XT[t] = 0.0f;                      // tv-pair accumulator (pre-MFMA barrier)

    // ---- stripe pipeline: 8 sets x 64 ranks
    {
        const char* Hb = (const char*)H + j16 * 16;
        // per-wave MFMA role (fixed across sets)
        const int wbs = wave >> 3;          // batch
        const int rt  = (wave >> 1) & 3;    // row-tile
        const int ch  = wave & 1;           // col half (2 col-tiles)
        const int col0 = ch * 32 + j16, col1 = col0 + 16;
        const float bc0 = b2[col0], wc0 = W3[col0];
        const float bc1 = b2[col1], wc1 = W3[col1];
        const hlf8 bf00 = *(const hlf8*)&W2T[col0 * HD + g16 * 8];
        const hlf8 bf01 = *(const hlf8*)&W2T[col0 * HD + 32 + g16 * 8];
        const hlf8 bf10 = *(const hlf8*)&W2T[col1 * HD + g16 * 8];
        const hlf8 bf11 = *(const hlf8*)&W2T[col1 * HD + 32 + g16 * 8];

        #pragma unroll 1
        for (int s = 0; s < 8; ++s) {
            // SpMM2: agg2 pair-rows -> swizzled stripe
            {
                int r  = s * 64 + wave * 4 + g16;
                int lr = wave * 4 + g16;
                int e0 = sptr[r], e1 = sptr[r + 1];
                float a[8];
                #pragma unroll
                for (int j = 0; j < 8; ++j) a[j] = 0.0f;
                int e = e0;
                for (; e + 4 <= e1; e += 4) {
                    int2 qa = *(const int2*)&epkg[e];
                    int2 qb = *(const int2*)&epkg[e + 2];
                    uint4 g0, g1, g2, g3; float s0, s1, s2, s3;
                    HLD(g0, qa.x) HLD(g1, qa.y) HLD(g2, qb.x) HLD(g3, qb.y)
                    HSC(s0, qa.x) HSC(s1, qa.y) HSC(s2, qb.x) HSC(s3, qb.y)
                    MAC8(a, g0, s0) MAC8(a, g1, s1) MAC8(a, g2, s2) MAC8(a, g3, s3)
                }
                if (e < e1) {
                    int2 qa = *(const int2*)&epkg[e];
                    uint4 g0, g1; float s0, s1;
                    HLD(g0, qa.x) HLD(g1, qa.y)
                    HSC(s0, qa.x) HSC(s1, qa.y)
                    MAC8(a, g0, s0) MAC8(a, g1, s1)
                }
                uint4 ov;
                ov.x = __builtin_bit_cast(unsigned,
                           __builtin_amdgcn_cvt_pkrtz(a[0], a[1]));
                ov.y = __builtin_bit_cast(unsigned,
                           __builtin_amdgcn_cvt_pkrtz(a[2], a[3]));
                ov.z = __builtin_bit_cast(unsigned,
                           __builtin_amdgcn_cvt_pkrtz(a[4], a[5]));
                ov.w = __builtin_bit_cast(unsigned,
                           __builtin_amdgcn_cvt_pkrtz(a[6], a[7]));
                *(uint4*)((char*)SP + lr * 256 +
                          ((j16 * 16) ^ ((lr & 7) << 4))) = ov;
            }
            __syncthreads();
            // MFMA: stripe(64x64 per batch) @ W2; fused relu.W3 rowsum -> tv
            {
                const int arow = rt * 16 + j16;
                const char* rb = (const char*)SP + arow * 256;
                const int swz = (j16 & 7) << 4;
                hlf8 a0 = *(const hlf8*)(rb + ((wbs * 128 + g16 * 16) ^ swz));
                hlf8 a1 = *(const hlf8*)(rb + ((wbs * 128 + 64 + g16 * 16) ^ swz));
                f32x4 acc0 = (f32x4){0.f, 0.f, 0.f, 0.f};
                f32x4 acc1 = (f32x4){0.f, 0.f, 0.f, 0.f};
                acc0 = __builtin_amdgcn_mfma_f32_16x16x32_f16(a0, bf00, acc0, 0, 0, 0);
                acc0 = __builtin_amdgcn_mfma_f32_16x16x32_f16(a1, bf01, acc0, 0, 0, 0);
                acc1 = __builtin_amdgcn_mfma_f32_16x16x32_f16(a0, bf10, acc1, 0, 0, 0);
                acc1 = __builtin_amdgcn_mfma_f32_16x16x32_f16(a1, bf11, acc1, 0, 0, 0);
                #pragma unroll
                for (int i = 0; i < 4; ++i) {
                    float v = fmaxf(acc0[i] + bc0, 0.0f) * wc0
                            + fmaxf(acc1[i] + bc1, 0.0f) * wc1;
                    v += __shfl_xor(v, 1, 64);
                    v += __shfl_xor(v, 2, 64);
                    v += __shfl_xor(v, 4, 64);
                    v += __shfl_xor(v, 8, 64);
                    if (j16 == 0) {
                        int node = cmap[s * 64 + rt * 16 + g16 * 4 + i];
                        atomicAdd(&XT[wbs * NUM + node], v);
                    }
                }
            }
            __syncthreads();
        }
    }

    // ---- SpMM3: logits = S@tv + b3  (one (rank,batch) per thread)
    {
        int rk = t & 511, bs = t >> 9;
        int e0 = sptr[rk], e1 = sptr[rk + 1];
        const float* TVB = XT + bs * NUM;
        float acc = 0.0f;
        for (int e = e0; e < e1; ++e) {
            unsigned pe = (unsigned)epkg[e];
            acc = fmaf((float)__builtin_bit_cast(hlf2, pe)[0], TVB[pe >> 16], acc);
        }
        SLOG[bs * NUM + cmap[rk]] = acc + b3[0];
    }
    __syncthreads();

    // ---- softmax stats over [0, MAIN) for each element (waves 0 and 1)
    if (t < 128) {
        int bs = t >> 6, l = t & 63;
        float v = (l < MAIN) ? SLOG[bs * NUM + l] : -1e30f;
        float m = v;
        m = fmaxf(m, __shfl_xor(m, 1, 64));
        m = fmaxf(m, __shfl_xor(m, 2, 64));
        m = fmaxf(m, __shfl_xor(m, 4, 64));
        m = fmaxf(m, __shfl_xor(m, 8, 64));
        float ev = (l < MAIN) ? __expf(v - m) : 0.0f;
        ev += __shfl_xor(ev, 1, 64);
        ev += __shfl_xor(ev, 2, 64);
        ev += __shfl_xor(ev, 4, 64);
        ev += __shfl_xor(ev, 8, 64);
        if (l == 0) { SRED[bs * 2] = m; SRED[bs * 2 + 1] = ev; }
    }
    __syncthreads();

    {
        int rk = t & 511, bs = t >> 9;
        float l = SLOG[bs * NUM + rk];
        float o = (rk < MAIN) ? __expf(l - SRED[bs * 2]) / SRED[bs * 2 + 1]
                              : 1.0f / (1.0f + __expf(-l));
        out[(b0 + bs) * NUM + rk] = o;
    }
#undef MAC8
#undef E1LD
#undef E1SC
#undef HLD
#undef HSC
}

// ---------------------------------------------------------------------------
extern "C" void kernel_launch(void* const* d_in, const int* in_sizes, int n_in,
                              void* d_out, int out_size, void* d_ws, size_t ws_size,
                              hipStream_t stream) {
    const float* x    = (const float*)d_in[0];
    const float* emb  = (const float*)d_in[1];
    const float* W1   = (const float*)d_in[2];
    const float* b1   = (const float*)d_in[3];
    const float* W2   = (const float*)d_in[4];
    const float* b2   = (const float*)d_in[5];
    const float* W3   = (const float*)d_in[6];
    const float* b3   = (const float*)d_in[7];
    const int*   erow = (const int*)d_in[8];
    const int*   ecol = (const int*)d_in[9];

    char* ws = (char*)d_ws;
    int*   rsptr  = (int*)ws;                // 513 ints  [0, 2052)
    int*   colmap = (int*)(ws + 2176);       // 512 ints  [2176, 4224)
    int*   epk    = (int*)(ws + 4224);       // 4608 ints [4224, 22656)
    short* E1     = (short*)(ws + 22656);    // 32768 f16 [22656, 88192)
    short* W2T    = (short*)(ws + 88192);    // 4096 f16  [88192, 96384)

    prep_all<<<73, 512, 0, stream>>>(erow, ecol, emb, W1, W2,
                                     rsptr, colmap, epk, E1, W2T);
    gcn_body<<<NB / 2, 1024, 0, stream>>>(x, (const hlf*)E1, (const hlf*)W2T,
                                          b1, b2, W3, b3,
                                          rsptr, colmap, epk, (float*)d_out);
}